// Round 33
// baseline (414.304 us; speedup 1.0000x reference)
//
#include <hip/hip_runtime.h>
#include <cmath>

#define CH 64           // scan chunk length
#define NC 64           // 4096 / CH

typedef __bf16 bf16_t;
typedef __attribute__((ext_vector_type(8))) __bf16 bf16x8;
typedef __attribute__((ext_vector_type(4))) __bf16 bf16x4;
typedef __attribute__((ext_vector_type(4))) float f32x4;

// CK idiom: generic->AS1/AS3 via uintptr for global_load_lds (width 16).
// NOTE (m104): LDS dest must be LINEAR in lane order (base + lane*16).
#define GLOAD_LDS16(gp, lp)                                                     \
    __builtin_amdgcn_global_load_lds(                                           \
        (const __attribute__((address_space(1))) unsigned int*)(uintptr_t)(gp), \
        (__attribute__((address_space(3))) unsigned int*)(uintptr_t)(lp),       \
        16, 0, 0)

#define SCHED_FENCE() __builtin_amdgcn_sched_barrier(0)

// ---------------------------------------------------------------------------
// Mega t=0 split: hidden/in_proj_w/out_proj_w -> hi ONLY; wd/xpw -> pairs.
// ---------------------------------------------------------------------------
__global__ __launch_bounds__(256) void split5n(
    const float* __restrict__ a, bf16_t* __restrict__ ah, int n4a,
    const float* __restrict__ b, bf16_t* __restrict__ bh, int n4b,
    const float* __restrict__ c, bf16_t* __restrict__ ch, bf16_t* __restrict__ cl, int n4c,
    const float* __restrict__ d, bf16_t* __restrict__ dh, bf16_t* __restrict__ dl, int n4d,
    const float* __restrict__ e, bf16_t* __restrict__ eh, int n4e)
{
    int i = blockIdx.x * 256 + threadIdx.x;
    if (i < n4a) {
        const float4 v = ((const float4*)a)[i];
        bf16x4 hv = {(bf16_t)v.x, (bf16_t)v.y, (bf16_t)v.z, (bf16_t)v.w};
        ((bf16x4*)ah)[i] = hv;
        return;
    }
    i -= n4a;
    if (i < n4b) {
        const float4 v = ((const float4*)b)[i];
        bf16x4 hv = {(bf16_t)v.x, (bf16_t)v.y, (bf16_t)v.z, (bf16_t)v.w};
        ((bf16x4*)bh)[i] = hv;
        return;
    }
    i -= n4b;
    if (i >= n4c + n4d) {
        i -= n4c + n4d;
        if (i < n4e) {
            const float4 v = ((const float4*)e)[i];
            bf16x4 hv = {(bf16_t)v.x, (bf16_t)v.y, (bf16_t)v.z, (bf16_t)v.w};
            ((bf16x4*)eh)[i] = hv;
        }
        return;
    }
    const float* src; bf16_t* hp; bf16_t* lp;
    if (i < n4c) { src = c; hp = ch; lp = cl; }
    else         { i -= n4c; src = d; hp = dh; lp = dl; }

    const float4 v = ((const float4*)src)[i];
    const bf16_t h0 = (bf16_t)v.x, h1 = (bf16_t)v.y,
                 h2 = (bf16_t)v.z, h3 = (bf16_t)v.w;
    bf16x4 hv = {h0, h1, h2, h3};
    bf16x4 lv = {(bf16_t)(v.x - (float)h0), (bf16_t)(v.y - (float)h1),
                 (bf16_t)(v.z - (float)h2), (bf16_t)(v.w - (float)h3)};
    ((bf16x4*)hp)[i] = hv;
    ((bf16x4*)lp)[i] = lv;
}

// ---------------------------------------------------------------------------
// x_proj split-K reduce + dt-slice hi/lo emit.
// ---------------------------------------------------------------------------
__global__ __launch_bounds__(256) void add8_split(
    const float* __restrict__ p, float* __restrict__ o,
    bf16_t* __restrict__ dth, bf16_t* __restrict__ dtl,
    int n4, size_t stride4)
{
    const int i = blockIdx.x * 256 + threadIdx.x;
    if (i >= n4) return;
    float4 s = make_float4(0.f, 0.f, 0.f, 0.f);
#pragma unroll
    for (int k = 0; k < 8; ++k) {
        const float4 v = ((const float4*)p)[(size_t)k * stride4 + i];
        s.x += v.x; s.y += v.y; s.z += v.z; s.w += v.w;
    }
    ((float4*)o)[i] = s;

    const int col4 = i % 24;
    if (col4 < 16) {
        const int row = i / 24;
        const bf16_t h0 = (bf16_t)s.x, h1 = (bf16_t)s.y,
                     h2 = (bf16_t)s.z, h3 = (bf16_t)s.w;
        bf16x4 hv = {h0, h1, h2, h3};
        bf16x4 lv = {(bf16_t)(s.x - (float)h0), (bf16_t)(s.y - (float)h1),
                     (bf16_t)(s.z - (float)h2), (bf16_t)(s.w - (float)h3)};
        ((bf16x4*)dth)[(size_t)row * 16 + col4] = hv;
        ((bf16x4*)dtl)[(size_t)row * 16 + col4] = lv;
    }
}

// ---------------------------------------------------------------------------
// in_proj, 256x256 tile, 3-PHASE schedule with COUNTED vmcnt (T3+T4 proper):
//   512 thr / 8 waves (2M x 4N), BK=64, 128 KiB LDS double-buffered.
//   STAGE loads ordered by read time: early-6 (A rows0-63 + all B), late-2
//   (A rows64-127, read only at the a1 phase).  vmcnt(2) at iter end leaves
//   the late-2 flying; vmcnt(8) before the a1 phase drains them (10
//   outstanding in steady state).  Never vmcnt(0) mid-loop (m218 lesson).
//   Full 3-bit XOR swizzle (elem col ^= (row&7)<<3) -> conflict-free.
// ---------------------------------------------------------------------------
__global__ __launch_bounds__(512, 1) void in_proj_8ph(
    const bf16_t* __restrict__ Ah, const bf16_t* __restrict__ Wh,
    bf16_t* __restrict__ X, bf16_t* __restrict__ Z, int Ktot)
{
    // lds[buf][mat(0=A,1=B)][half][128*64]
    __shared__ __align__(16) bf16_t lds[2][2][2][128 * 64];

    const int tid  = threadIdx.x;
    const int lane = tid & 63;
    const int wid  = tid >> 6;
    const int wm   = wid >> 2;        // 0..1  (m-half of C)
    const int wn   = wid & 3;         // 0..3  (n-quarter of C)
    const int l16  = lane & 15;
    const int lhi  = lane >> 4;

    const int bm  = blockIdx.x * 256;
    const int bnW = blockIdx.y * 256;

    // staging geometry: per half-tile (128x64) each thread does 2 x 16B
    const int srow = tid >> 3;            // 0..63
    const int scol = (tid & 7) * 8;       // element col 0..56
    const int sflip = (srow & 7) << 3;    // full 3-bit swizzle (16B-slot XOR)

    f32x4 acc[8][4];
#pragma unroll
    for (int i = 0; i < 8; ++i)
#pragma unroll
        for (int j = 0; j < 4; ++j)
#pragma unroll
            for (int r = 0; r < 4; ++r) acc[i][j][r] = 0.f;

    const int NT = Ktot >> 6;   // K-tiles of 64

    // ordered stage: early-6 first (A j=0 both halves, all 4 B), late-2 last
    // (A j=1 both halves, read only by the a1 phase).
    auto STAGE_TILE = [&](int pbuf, int kt) {
        const int kc = kt * 64 + (scol ^ sflip);
#pragma unroll
        for (int h = 0; h < 2; ++h) {   // A j=0: rows 0-63 of each half
            const int row = h * 128 + srow;
            GLOAD_LDS16(Ah + (size_t)(bm + row) * Ktot + kc,
                        (char*)&lds[pbuf][0][h][0] + tid * 16);
        }
#pragma unroll
        for (int h = 0; h < 2; ++h)     // B: all rows (read at ph0/ph1)
#pragma unroll
            for (int j = 0; j < 2; ++j) {
                const int row = h * 128 + j * 64 + srow;
                GLOAD_LDS16(Wh + (size_t)(bnW + row) * Ktot + kc,
                            (char*)&lds[pbuf][1][h][0] + (j * 512 + tid) * 16);
            }
#pragma unroll
        for (int h = 0; h < 2; ++h) {   // A j=1: rows 64-127 (a1 phase only)
            const int row = h * 128 + 64 + srow;
            GLOAD_LDS16(Ah + (size_t)(bm + row) * Ktot + kc,
                        (char*)&lds[pbuf][0][h][0] + (512 + tid) * 16);
        }
    };

    const int rflip = (l16 & 7) << 3;     // read-side swizzle (row&7 == l16&7)
    auto A_FRAG = [&](int p, int fm, int kk) -> bf16x8 {
        return *(const bf16x8*)&lds[p][0][wm]
            [(fm * 16 + l16) * 64 + ((kk * 32 + lhi * 8) ^ rflip)];
    };
    auto B_FRAG = [&](int p, int fn, int kk) -> bf16x8 {
        return *(const bf16x8*)&lds[p][1][wn >> 1]
            [((wn & 1) * 64 + fn * 16 + l16) * 64 + ((kk * 32 + lhi * 8) ^ rflip)];
    };

    // prologue: stage tile 0, full drain, barrier
    STAGE_TILE(0, 0);
    SCHED_FENCE();
    asm volatile("s_waitcnt vmcnt(0)" ::: "memory");
    __builtin_amdgcn_s_barrier();
    SCHED_FENCE();

    for (int kt = 0; kt < NT; ++kt) {
        const int p  = kt & 1;
        const int pn = p ^ 1;
        bf16x8 a0[4][2], a1[4][2], b0[2][2], b1[2][2];

        // ---- phase 0: read a0,b0; stage next tile (ordered) ----
#pragma unroll
        for (int f = 0; f < 4; ++f)
#pragma unroll
            for (int kk = 0; kk < 2; ++kk) a0[f][kk] = A_FRAG(p, f, kk);
#pragma unroll
        for (int f = 0; f < 2; ++f)
#pragma unroll
            for (int kk = 0; kk < 2; ++kk) b0[f][kk] = B_FRAG(p, f, kk);
        if (kt + 1 < NT) STAGE_TILE(pn, kt + 1);
        SCHED_FENCE();
        __builtin_amdgcn_s_barrier();
        SCHED_FENCE();
        __builtin_amdgcn_s_setprio(1);
#pragma unroll
        for (int f = 0; f < 4; ++f)
#pragma unroll
            for (int n = 0; n < 2; ++n)
#pragma unroll
                for (int kk = 0; kk < 2; ++kk)
                    acc[f][n] = __builtin_amdgcn_mfma_f32_16x16x32_bf16(
                        a0[f][kk], b0[n][kk], acc[f][n], 0, 0, 0);
        __builtin_amdgcn_s_setprio(0);
        SCHED_FENCE();
        __builtin_amdgcn_s_barrier();
        SCHED_FENCE();

        // ---- phase 1: read b1; MFMA a0 x b1; guard late-2 of tile kt ----
#pragma unroll
        for (int f = 0; f < 2; ++f)
#pragma unroll
            for (int kk = 0; kk < 2; ++kk) b1[f][kk] = B_FRAG(p, f + 2, kk);
        SCHED_FENCE();
        __builtin_amdgcn_s_barrier();
        SCHED_FENCE();
        __builtin_amdgcn_s_setprio(1);
#pragma unroll
        for (int f = 0; f < 4; ++f)
#pragma unroll
            for (int n = 0; n < 2; ++n)
#pragma unroll
                for (int kk = 0; kk < 2; ++kk)
                    acc[f][n + 2] = __builtin_amdgcn_mfma_f32_16x16x32_bf16(
                        a0[f][kk], b1[n][kk], acc[f][n + 2], 0, 0, 0);
        __builtin_amdgcn_s_setprio(0);
        SCHED_FENCE();
        // late-2 A loads of CURRENT tile kt must land before a1 reads.
        // steady state: 2 old + 8 new outstanding -> vmcnt(8); if nothing
        // was staged this iter (kt+1==NT), only 2 outstanding -> vmcnt(0).
        if (kt + 1 < NT) { asm volatile("s_waitcnt vmcnt(8)" ::: "memory"); }
        else             { asm volatile("s_waitcnt vmcnt(0)" ::: "memory"); }
        SCHED_FENCE();
        __builtin_amdgcn_s_barrier();
        SCHED_FENCE();

        // ---- phase 2: read a1; MFMA a1 x b0 + a1 x b1; counted drain ----
#pragma unroll
        for (int f = 0; f < 4; ++f)
#pragma unroll
            for (int kk = 0; kk < 2; ++kk) a1[f][kk] = A_FRAG(p, f + 4, kk);
        SCHED_FENCE();
        __builtin_amdgcn_s_barrier();
        SCHED_FENCE();
        __builtin_amdgcn_s_setprio(1);
#pragma unroll
        for (int f = 0; f < 4; ++f)
#pragma unroll
            for (int n = 0; n < 2; ++n)
#pragma unroll
                for (int kk = 0; kk < 2; ++kk)
                    acc[f + 4][n] = __builtin_amdgcn_mfma_f32_16x16x32_bf16(
                        a1[f][kk], b0[n][kk], acc[f + 4][n], 0, 0, 0);
#pragma unroll
        for (int f = 0; f < 4; ++f)
#pragma unroll
            for (int n = 0; n < 2; ++n)
#pragma unroll
                for (int kk = 0; kk < 2; ++kk)
                    acc[f + 4][n + 2] = __builtin_amdgcn_mfma_f32_16x16x32_bf16(
                        a1[f][kk], b1[n][kk], acc[f + 4][n + 2], 0, 0, 0);
        __builtin_amdgcn_s_setprio(0);
        SCHED_FENCE();
        // drain early-6 of tile kt+1; leave its late-2 flying into next iter.
        asm volatile("s_waitcnt vmcnt(2)" ::: "memory");
        SCHED_FENCE();
        __builtin_amdgcn_s_barrier();
        SCHED_FENCE();
    }

    bf16_t* outp = (blockIdx.y < 8) ? X : Z;
    const int bnC = ((blockIdx.y < 8) ? blockIdx.y : (blockIdx.y - 8)) * 256;
#pragma unroll
    for (int fm = 0; fm < 8; ++fm) {
        const int row0 = bm + wm * 128 + fm * 16 + lhi * 4;
#pragma unroll
        for (int fn = 0; fn < 4; ++fn) {
            const int col = bnC + wn * 64 + fn * 16 + l16;
#pragma unroll
            for (int r = 0; r < 4; ++r)
                outp[(size_t)(row0 + r) * 2048 + col] = (bf16_t)acc[fm][fn][r];
        }
    }
}

// ---------------------------------------------------------------------------
// dt_proj: 3-term MFMA (dt pair x wd pair), K=64; softplus; bf16 OUTPUT.
// 128x128 tile, BK=32, 48 MFMA/step.
// ---------------------------------------------------------------------------
__global__ __launch_bounds__(256) void gemm_mfma3dt(
    const bf16_t* __restrict__ Ah, const bf16_t* __restrict__ Al,
    const bf16_t* __restrict__ Bh, const bf16_t* __restrict__ Bl,
    bf16_t* __restrict__ C, const float* __restrict__ bias,
    int Ktot, int ldc)
{
    __shared__ __align__(16) bf16_t Ash[128 * 32];
    __shared__ __align__(16) bf16_t Asl[128 * 32];
    __shared__ __align__(16) bf16_t Bsh[128 * 32];
    __shared__ __align__(16) bf16_t Bsl[128 * 32];

    const int tid  = threadIdx.x;
    const int lane = tid & 63;
    const int w    = tid >> 6;
    const int wr   = (w >> 1) * 64;
    const int wc   = (w & 1) * 64;
    const int bm   = blockIdx.x * 128;
    const int bn   = blockIdx.y * 128;
    const int l16  = lane & 15;
    const int lhi  = lane >> 4;

    f32x4 acc[4][4];
#pragma unroll
    for (int i = 0; i < 4; ++i)
#pragma unroll
        for (int j = 0; j < 4; ++j)
#pragma unroll
            for (int r = 0; r < 4; ++r) acc[i][j][r] = 0.f;

    const int srow0 = tid >> 2;
    const int sks   = (tid & 3) << 3;
    const int ldsb0 = tid * 16;

    for (int k0 = 0; k0 < Ktot; k0 += 32) {
        __syncthreads();
#pragma unroll
        for (int call = 0; call < 2; ++call) {
            const int row = srow0 + call * 64;
            const int wb  = ldsb0 + call * 4096;
            const size_t aoff = (size_t)(bm + row) * Ktot + k0 + sks;
            const size_t boff = (size_t)(bn + row) * Ktot + k0 + sks;
            GLOAD_LDS16(Ah + aoff, (char*)Ash + wb);
            GLOAD_LDS16(Al + aoff, (char*)Asl + wb);
            GLOAD_LDS16(Bh + boff, (char*)Bsh + wb);
            GLOAD_LDS16(Bl + boff, (char*)Bsl + wb);
        }
        __syncthreads();

        bf16x8 ah[4], al[4], bh[4], bl[4];
#pragma unroll
        for (int f = 0; f < 4; ++f) {
            const int ar = (wr + f * 16 + l16) * 32 + lhi * 8;
            const int br = (wc + f * 16 + l16) * 32 + lhi * 8;
            ah[f] = *(const bf16x8*)&Ash[ar];
            al[f] = *(const bf16x8*)&Asl[ar];
            bh[f] = *(const bf16x8*)&Bsh[br];
            bl[f] = *(const bf16x8*)&Bsl[br];
        }
#pragma unroll
        for (int fm = 0; fm < 4; ++fm)
#pragma unroll
            for (int fn = 0; fn < 4; ++fn) {
                acc[fm][fn] = __builtin_amdgcn_mfma_f32_16x16x32_bf16(
                    ah[fm], bh[fn], acc[fm][fn], 0, 0, 0);
                acc[fm][fn] = __builtin_amdgcn_mfma_f32_16x16x32_bf16(
                    al[fm], bh[fn], acc[fm][fn], 0, 0, 0);
                acc[fm][fn] = __builtin_amdgcn_mfma_f32_16x16x32_bf16(
                    ah[fm], bl[fn], acc[fm][fn], 0, 0, 0);
            }
    }

#pragma unroll
    for (int fm = 0; fm < 4; ++fm) {
        const int row0 = bm + wr + fm * 16 + lhi * 4;
#pragma unroll
        for (int fn = 0; fn < 4; ++fn) {
            const int col = bn + wc + fn * 16 + l16;
#pragma unroll
            for (int r = 0; r < 4; ++r) {
                float v = acc[fm][fn][r] + bias[col];
                v = (v > 20.f) ? v : log1pf(expf(v));
                C[(size_t)(row0 + r) * ldc + col] = (bf16_t)v;
            }
        }
    }
}

// ---------------------------------------------------------------------------
// x_proj, 2-TERM MFMA (A single bf16 x B pair), split-K.
// ---------------------------------------------------------------------------
__global__ __launch_bounds__(256) void gemm_mfma2x(
    const bf16_t* __restrict__ Ah,
    const bf16_t* __restrict__ Bh, const bf16_t* __restrict__ Bl,
    float* __restrict__ C, int Ktot, int Ksplit, size_t partStride)
{
    __shared__ __align__(16) bf16_t Ash[128 * 32];
    __shared__ __align__(16) bf16_t Bsh[128 * 32];
    __shared__ __align__(16) bf16_t Bsl[128 * 32];

    const int tid  = threadIdx.x;
    const int lane = tid & 63;
    const int w    = tid >> 6;
    const int wr   = (w >> 1) * 64;
    const int wc   = (w & 1) * 64;
    const int bm   = blockIdx.x * 128;
    const int l16  = lane & 15;
    const int lhi  = lane >> 4;

    f32x4 acc[4][4];
#pragma unroll
    for (int i = 0; i < 4; ++i)
#pragma unroll
        for (int j = 0; j < 4; ++j)
#pragma unroll
            for (int r = 0; r < 4; ++r) acc[i][j][r] = 0.f;

    const int srow0 = tid >> 2;
    const int sks   = (tid & 3) << 3;
    const int ldsb0 = tid * 16;

    const int kBeg = blockIdx.z * Ksplit;
    const int kEnd = kBeg + Ksplit;

    for (int k0 = kBeg; k0 < kEnd; k0 += 32) {
        __syncthreads();
#pragma unroll
        for (int call = 0; call < 2; ++call) {
            const int row  = srow0 + call * 64;
            const int brow = (row < 96) ? row : 95;
            const int wb   = ldsb0 + call * 4096;
            const size_t aoff = (size_t)(bm + row) * Ktot + k0 + sks;
            const size_t boff = (size_t)brow * Ktot + k0 + sks;
            GLOAD_LDS16(Ah + aoff, (char*)Ash + wb);
            GLOAD_LDS16(Bh + boff, (char*)Bsh + wb);
            GLOAD_LDS16(Bl + boff, (char*)Bsl + wb);
        }
        __syncthreads();

        bf16x8 ah[4], bh[4], bl[4];
#pragma unroll
        for (int f = 0; f < 4; ++f) {
            const int ar = (wr + f * 16 + l16) * 32 + lhi * 8;
            const int br = (wc + f * 16 + l16) * 32 + lhi * 8;
            ah[f] = *(const bf16x8*)&Ash[ar];
            bh[f] = *(const bf16x8*)&Bsh[br];
            bl[f] = *(const bf16x8*)&Bsl[br];
        }
#pragma unroll
        for (int fm = 0; fm < 4; ++fm)
#pragma unroll
            for (int fn = 0; fn < 4; ++fn) {
                acc[fm][fn] = __builtin_amdgcn_mfma_f32_16x16x32_bf16(
                    ah[fm], bh[fn], acc[fm][fn], 0, 0, 0);
                acc[fm][fn] = __builtin_amdgcn_mfma_f32_16x16x32_bf16(
                    ah[fm], bl[fn], acc[fm][fn], 0, 0, 0);
            }
    }

    float* Cp = C + (size_t)blockIdx.z * partStride;
#pragma unroll
    for (int fm = 0; fm < 4; ++fm) {
        const int row0 = bm + wr + fm * 16 + lhi * 4;
#pragma unroll
        for (int fn = 0; fn < 4; ++fn) {
            const int col = wc + fn * 16 + l16;
            if (col < 96) {
#pragma unroll
                for (int r = 0; r < 4; ++r)
                    Cp[(size_t)(row0 + r) * 96 + col] = acc[fm][fn][r];
            }
        }
    }
}

// ---------------------------------------------------------------------------
// out_proj (1-TERM, 128x128 tile, NO SPLIT-K): C = Ah.Bh^T direct to out.
// ---------------------------------------------------------------------------
__global__ __launch_bounds__(256) void gemm_mfma1o128(
    const bf16_t* __restrict__ Ah, const bf16_t* __restrict__ Bh,
    float* __restrict__ C, int K, int ldc)
{
    __shared__ __align__(16) bf16_t Ash[128 * 32];
    __shared__ __align__(16) bf16_t Bsh[128 * 32];

    const int tid  = threadIdx.x;
    const int lane = tid & 63;
    const int w    = tid >> 6;
    const int wr   = (w >> 1) * 64;
    const int wc   = (w & 1) * 64;
    const int bm   = blockIdx.x * 128;
    const int bn   = blockIdx.y * 128;
    const int l16  = lane & 15;
    const int lhi  = lane >> 4;

    f32x4 acc[4][4];
#pragma unroll
    for (int i = 0; i < 4; ++i)
#pragma unroll
        for (int j = 0; j < 4; ++j)
#pragma unroll
            for (int r = 0; r < 4; ++r) acc[i][j][r] = 0.f;

    const int srow0 = tid >> 2;
    const int sks   = (tid & 3) << 3;
    const int ldsb0 = tid * 16;

    for (int k0 = 0; k0 < K; k0 += 32) {
        __syncthreads();
#pragma unroll
        for (int call = 0; call < 2; ++call) {
            const int row = srow0 + call * 64;
            const int wb  = ldsb0 + call * 4096;
            GLOAD_LDS16(Ah + (size_t)(bm + row) * K + k0 + sks, (char*)Ash + wb);
            GLOAD_LDS16(Bh + (size_t)(bn + row) * K + k0 + sks, (char*)Bsh + wb);
        }
        __syncthreads();

        bf16x8 af[4], bfr[4];
#pragma unroll
        for (int f = 0; f < 4; ++f) {
            af[f]  = *(const bf16x8*)&Ash[(wr + f * 16 + l16) * 32 + lhi * 8];
            bfr[f] = *(const bf16x8*)&Bsh[(wc + f * 16 + l16) * 32 + lhi * 8];
        }
#pragma unroll
        for (int fm = 0; fm < 4; ++fm)
#pragma unroll
            for (int fn = 0; fn < 4; ++fn)
                acc[fm][fn] = __builtin_amdgcn_mfma_f32_16x16x32_bf16(
                    af[fm], bfr[fn], acc[fm][fn], 0, 0, 0);
    }

#pragma unroll
    for (int fm = 0; fm < 4; ++fm) {
        const int row0 = bm + wr + fm * 16 + lhi * 4;
#pragma unroll
        for (int fn = 0; fn < 4; ++fn) {
            const int col = bn + wc + fn * 16 + l16;
#pragma unroll
            for (int r = 0; r < 4; ++r)
                C[(size_t)(row0 + r) * ldc + col] = acc[fm][fn][r];
        }
    }
}

// ---------------------------------------------------------------------------
// Depthwise causal conv (width 4) + bias + SiLU; INPUT bf16, 8 ch/thread;
// output SINGLE bf16.  SiLU via fast rcp (1-ulp; invisible under bf16).
// ---------------------------------------------------------------------------
__global__ __launch_bounds__(256) void conv_silu8s(
    const bf16_t* __restrict__ xin, const float* __restrict__ w,
    const float* __restrict__ bias,
    bf16_t* __restrict__ xh,
    int L, int D)
{
    const long long e8 = (long long)blockIdx.x * 256 + threadIdx.x;
    const int Dq = D >> 3;
    const int dq = (int)(e8 % Dq);
    const long long bl = e8 / Dq;
    const int l = (int)(bl % L);
    const int d = dq << 3;
    const long long base = bl * D + d;

    float t0[8], t1[8], t2[8], t3[8];
    {
        const bf16x8 v = *(const bf16x8*)&xin[base];
#pragma unroll
        for (int j = 0; j < 8; ++j) t0[j] = (float)v[j];
    }
    if (l >= 1) { const bf16x8 v = *(const bf16x8*)&xin[base - D];
#pragma unroll
        for (int j = 0; j < 8; ++j) t1[j] = (float)v[j];
    } else { for (int j = 0; j < 8; ++j) t1[j] = 0.f; }
    if (l >= 2) { const bf16x8 v = *(const bf16x8*)&xin[base - 2 * D];
#pragma unroll
        for (int j = 0; j < 8; ++j) t2[j] = (float)v[j];
    } else { for (int j = 0; j < 8; ++j) t2[j] = 0.f; }
    if (l >= 3) { const bf16x8 v = *(const bf16x8*)&xin[base - 3 * D];
#pragma unroll
        for (int j = 0; j < 8; ++j) t3[j] = (float)v[j];
    } else { for (int j = 0; j < 8; ++j) t3[j] = 0.f; }

    bf16x8 hv;
#pragma unroll
    for (int j = 0; j < 8; ++j) {
        const float4 wv = *(const float4*)&w[(d + j) * 4];
        float acc = bias[d + j];
        acc = fmaf(wv.w, t0[j], acc);
        acc = fmaf(wv.z, t1[j], acc);
        acc = fmaf(wv.y, t2[j], acc);
        acc = fmaf(wv.x, t3[j], acc);
        const float o = acc * __builtin_amdgcn_rcpf(1.f + __expf(-acc));
        hv[j] = (bf16_t)o;
    }
    *(bf16x8*)&xh[base] = hv;
}

// ---------------------------------------------------------------------------
// Scan pass 1 (per-channel): x bf16 single, dt bf16.  CH=64.
// B read as 4 x ds_read_b128 per timestep.
// ---------------------------------------------------------------------------
__global__ __launch_bounds__(256) void scan_local2(
    const bf16_t* __restrict__ xh,
    const bf16_t* __restrict__ dtb,
    const float* __restrict__ xdbl,  const float* __restrict__ A_log,
    float* __restrict__ Sbuf, float* __restrict__ Pbuf)
{
    __shared__ __align__(16) float Bs[CH][16];

    const int d = blockIdx.x * 256 + threadIdx.x;
    const int c = blockIdx.y;
    const int b = blockIdx.z;
    const long long rowBase = (long long)b * 4096 + (long long)c * CH;

    {
        const int e = threadIdx.x;
        const int i = e >> 2, j = (e & 3) << 2;
        *(float4*)&Bs[i][j] = *(const float4*)&xdbl[(rowBase + i) * 96 + 64 + j];
    }
    __syncthreads();

    float a[16], S[16];
#pragma unroll
    for (int n = 0; n < 16; ++n) {
        a[n] = -__expf(A_log[d * 16 + n]);
        S[n] = 0.f;
    }
    float sumdt = 0.f;

    for (int i = 0; i < CH; ++i) {
        const long long row = rowBase + i;
        const float dtv = (float)dtb[row * 2048 + d];
        const float xv  = (float)xh[row * 2048 + d];
        const float u   = dtv * xv;
        sumdt += dtv;

        const f32x4 bv0 = *(const f32x4*)&Bs[i][0];
        const f32x4 bv1 = *(const f32x4*)&Bs[i][4];
        const f32x4 bv2 = *(const f32x4*)&Bs[i][8];
        const f32x4 bv3 = *(const f32x4*)&Bs[i][12];
        float bb[16];
#pragma unroll
        for (int q = 0; q < 4; ++q) {
            bb[q]      = bv0[q];
            bb[4 + q]  = bv1[q];
            bb[8 + q]  = bv2[q];
            bb[12 + q] = bv3[q];
        }
#pragma unroll
        for (int n = 0; n < 16; ++n) {
            const float dA = __expf(dtv * a[n]);
            S[n] = fmaf(S[n], dA, u * bb[n]);
        }
    }

    const size_t base = ((((size_t)b * NC + c) * 2048) + d) * 16;
#pragma unroll
    for (int k = 0; k < 4; ++k) {
        *(float4*)&Sbuf[base + k * 4] =
            make_float4(S[k*4], S[k*4+1], S[k*4+2], S[k*4+3]);
        *(float4*)&Pbuf[base + k * 4] =
            make_float4(__expf(sumdt * a[k*4]),   __expf(sumdt * a[k*4+1]),
                        __expf(sumdt * a[k*4+2]), __expf(sumdt * a[k*4+3]));
    }
}

// ---------------------------------------------------------------------------
// Pass 2: sequential prefix over NC=64 chunks.
// ---------------------------------------------------------------------------
__global__ __launch_bounds__(256) void scan_chunk_prefix(
    float* __restrict__ Sbuf, const float* __restrict__ Pbuf)
{
    const int tid = blockIdx.x * 256 + threadIdx.x;
    const int b  = tid >> 15;
    const int dn = tid & 32767;

    float H = 0.f;
    for (int c = 0; c < NC; ++c) {
        const size_t idx = ((size_t)b * NC + c) * 32768 + dn;
        const float S = Sbuf[idx];
        const float P = Pbuf[idx];
        Sbuf[idx] = H;
        H = fmaf(P, H, S);
    }
}

// ---------------------------------------------------------------------------
// Scan pass 3: x single, dt bf16, z bf16; y written bf16 in-place over xh.
// B/C read as 8 x ds_read_b128 per timestep; SiLU via rcp.  CH=64.
// ---------------------------------------------------------------------------
__global__ __launch_bounds__(256) void scan_final2(
    const bf16_t* __restrict__ xh,
    const bf16_t* __restrict__ dtb,
    const float* __restrict__ xdbl,  const float* __restrict__ A_log,
    const float* __restrict__ Dp,    const bf16_t* __restrict__ z,
    const float* __restrict__ Hbuf,  bf16_t* __restrict__ y)
{
    __shared__ __align__(16) float BCs[CH][32];

    const int d = blockIdx.x * 256 + threadIdx.x;
    const int c = blockIdx.y;
    const int b = blockIdx.z;
    const long long rowBase = (long long)b * 4096 + (long long)c * CH;

#pragma unroll
    for (int k = 0; k < 2; ++k) {
        const int e = k * 256 + threadIdx.x;
        const int i = e >> 3, j = (e & 7) << 2;
        *(float4*)&BCs[i][j] = *(const float4*)&xdbl[(rowBase + i) * 96 + 64 + j];
    }
    __syncthreads();

    float a[16], h[16];
    const size_t hbase = ((((size_t)b * NC + c) * 2048) + d) * 16;
#pragma unroll
    for (int k = 0; k < 4; ++k) {
        const float4 hv = *(const float4*)&Hbuf[hbase + k * 4];
        h[k*4] = hv.x; h[k*4+1] = hv.y; h[k*4+2] = hv.z; h[k*4+3] = hv.w;
    }
#pragma unroll
    for (int n = 0; n < 16; ++n) a[n] = -__expf(A_log[d * 16 + n]);
    const float Dv = Dp[d];

    for (int i = 0; i < CH; ++i) {
        const long long row = rowBase + i;
        const float dtv = (float)dtb[row * 2048 + d];
        const float xv  = (float)xh[row * 2048 + d];
        const float u   = dtv * xv;

        const f32x4 bv0 = *(const f32x4*)&BCs[i][0];
        const f32x4 bv1 = *(const f32x4*)&BCs[i][4];
        const f32x4 bv2 = *(const f32x4*)&BCs[i][8];
        const f32x4 bv3 = *(const f32x4*)&BCs[i][12];
        const f32x4 cv0 = *(const f32x4*)&BCs[i][16];
        const f32x4 cv1 = *(const f32x4*)&BCs[i][20];
        const f32x4 cv2 = *(const f32x4*)&BCs[i][24];
        const f32x4 cv3 = *(const f32x4*)&BCs[i][28];
        float bb[16], cc[16];
#pragma unroll
        for (int q = 0; q < 4; ++q) {
            bb[q]      = bv0[q];  cc[q]      = cv0[q];
            bb[4 + q]  = bv1[q];  cc[4 + q]  = cv1[q];
            bb[8 + q]  = bv2[q];  cc[8 + q]  = cv2[q];
            bb[12 + q] = bv3[q];  cc[12 + q] = cv3[q];
        }

        float acc = 0.f;
#pragma unroll
        for (int n = 0; n < 16; ++n) {
            const float dA = __expf(dtv * a[n]);
            h[n] = fmaf(h[n], dA, u * bb[n]);
            acc  = fmaf(h[n], cc[n], acc);
        }
        const float zv = (float)z[row * 2048 + d];
        float yv = acc + xv * Dv;
        yv = yv * (zv * __builtin_amdgcn_rcpf(1.f + __expf(-zv)));
        y[row * 2048 + d] = (bf16_t)yv;
    }
}

// ---------------------------------------------------------------------------
extern "C" void kernel_launch(void* const* d_in, const int* in_sizes, int n_in,
                              void* d_out, int out_size, void* d_ws, size_t ws_size,
                              hipStream_t stream)
{
    const float* hidden     = (const float*)d_in[0];
    const float* in_proj_w  = (const float*)d_in[1];
    const float* conv_w     = (const float*)d_in[2];
    const float* conv_b     = (const float*)d_in[3];
    const float* x_proj_w   = (const float*)d_in[4];
    const float* dt_proj_w  = (const float*)d_in[5];
    const float* dt_proj_b  = (const float*)d_in[6];
    const float* A_log      = (const float*)d_in[7];
    const float* Dvec       = (const float*)d_in[8];
    const float* out_proj_w = (const float*)d_in[9];
    float* out = (float*)d_out;

    const int L = 4096, dinner = 2048, dmodel = 1024;
    const int M = 2 * L;  // 8192

    // ---- workspace layout (R2 footprint preserved) ----
    float* z     = (float*)d_ws;
    float* xraw  = z     + (size_t)M * dinner;
    float* xconv = xraw  + (size_t)M * dinner;
    float* xdbl  = xconv + (size_t)M * dinner;
    float* Sbuf  = xdbl  + (size_t)M * 96;             // 16.8 MB region

    bf16_t* w1_h  = (bf16_t*)Sbuf;                     // hi only, 8.4 MB (t0..in_proj)
    bf16_t* hid_h = (bf16_t*)xconv;
    bf16_t* zb    = (bf16_t*)z;
    bf16_t* Xb    = (bf16_t*)xraw;                     // x bf16 (33.5 MB)
    bf16_t* xc_h  = (bf16_t*)xconv;                    // conv out, single bf16
    float*  xp_part = xraw;                            // x_proj partials (Xb dead post-conv)
    bf16_t* dtb  = (bf16_t*)xraw;                      // dt bf16 (partials dead post-add8)
    bf16_t* dth  = (bf16_t*)Sbuf;
    bf16_t* dtl  = dth + (size_t)M * 64;
    bf16_t* wdh  = (bf16_t*)out;                       // d_out region (dead pre-step6)
    bf16_t* wdl  = wdh + (size_t)dinner * 64;
    bf16_t* xpwh = (bf16_t*)xdbl;                      // xdbl region (pre-add8)
    bf16_t* xpwl = xpwh + (size_t)96 * dinner;
    bf16_t* w2_h = zb + (size_t)M * dinner;            // z + 33.5 MB (hi only)
    float*  Pbuf = (float*)(w2_h + (size_t)dmodel * dinner);  // z + 37.7 MB

    // ---- 0. mega t=0 split ----
    const int n4a = M * dmodel / 4;
    const int n4b = 2 * dinner * dmodel / 4;
    const int n4c = dinner * 64 / 4;
    const int n4d = 96 * dinner / 4;
    const int n4e = dmodel * dinner / 4;
    split5n<<<(n4a + n4b + n4c + n4d + n4e + 255) / 256, 256, 0, stream>>>(
        hidden, hid_h, n4a,
        in_proj_w, w1_h, n4b,
        dt_proj_w, wdh, wdl, n4c,
        x_proj_w, xpwh, xpwl, n4d,
        out_proj_w, w2_h, n4e);

    // ---- 1. in_proj (256^2 3-phase counted-vmcnt; x bf16 | z bf16) ----
    in_proj_8ph<<<dim3(M / 256, 16), 512, 0, stream>>>(
        hid_h, w1_h, Xb, zb, dmodel);

    // ---- 2. conv + bias + SiLU (bf16 in) -> bf16 single ----
    conv_silu8s<<<(M * (long long)dinner / 8) / 256, 256, 0, stream>>>(
        Xb, conv_w, conv_b, xc_h, L, dinner);

    // ---- 3. x_proj (2-term MFMA, split-K=8) ----
    gemm_mfma2x<<<dim3(M / 128, 1, 8), 256, 0, stream>>>(
        xc_h, xpwh, xpwl, xp_part, dinner, dinner / 8, (size_t)M * 96);
    add8_split<<<(M * 96 / 4 + 255) / 256, 256, 0, stream>>>(
        xp_part, xdbl, dth, dtl, M * 96 / 4, (size_t)M * 96 / 4);

    // ---- 4. dt_proj (3-term MFMA, K=64) -> dt bf16 (over dead partials) ----
    gemm_mfma3dt<<<dim3(M / 128, 2048 / 128), 256, 0, stream>>>(
        dth, dtl, wdh, wdl, dtb, dt_proj_b, 64, 2048);

    // ---- 5. chunked selective scan (CH=64) ----
    scan_local2<<<dim3(dinner / 256, NC, 2), 256, 0, stream>>>(
        xc_h, dtb, xdbl, A_log, Sbuf, Pbuf);
    scan_chunk_prefix<<<256, 256, 0, stream>>>(Sbuf, Pbuf);
    scan_final2<<<dim3(dinner / 256, NC, 2), 256, 0, stream>>>(
        xc_h, dtb, xdbl, A_log, Dvec, zb, Sbuf, xc_h);

    // ---- 6. out_proj (1-term, 128x128 tile, direct write) ----
    gemm_mfma1o128<<<dim3(M / 128, 1024 / 128), 256, 0, stream>>>(
        xc_h, w2_h, out, dinner, 1024);
}

// Round 34
// 413.429 us; speedup vs baseline: 1.0021x; 1.0021x over previous
//
#include <hip/hip_runtime.h>
#include <cmath>

#define CH 64           // scan chunk length
#define NC 64           // 4096 / CH

typedef __bf16 bf16_t;
typedef __attribute__((ext_vector_type(8))) __bf16 bf16x8;
typedef __attribute__((ext_vector_type(4))) __bf16 bf16x4;
typedef __attribute__((ext_vector_type(4))) float f32x4;

// CK idiom: generic->AS1/AS3 via uintptr for global_load_lds (width 16).
// NOTE (m104): LDS dest must be LINEAR in lane order (base + lane*16).
#define GLOAD_LDS16(gp, lp)                                                     \
    __builtin_amdgcn_global_load_lds(                                           \
        (const __attribute__((address_space(1))) unsigned int*)(uintptr_t)(gp), \
        (__attribute__((address_space(3))) unsigned int*)(uintptr_t)(lp),       \
        16, 0, 0)

#define SCHED_FENCE() __builtin_amdgcn_sched_barrier(0)

// ---------------------------------------------------------------------------
// Mega t=0 split: hidden/in_proj_w/out_proj_w -> hi ONLY; wd/xpw -> pairs.
// ---------------------------------------------------------------------------
__global__ __launch_bounds__(256) void split5n(
    const float* __restrict__ a, bf16_t* __restrict__ ah, int n4a,
    const float* __restrict__ b, bf16_t* __restrict__ bh, int n4b,
    const float* __restrict__ c, bf16_t* __restrict__ ch, bf16_t* __restrict__ cl, int n4c,
    const float* __restrict__ d, bf16_t* __restrict__ dh, bf16_t* __restrict__ dl, int n4d,
    const float* __restrict__ e, bf16_t* __restrict__ eh, int n4e)
{
    int i = blockIdx.x * 256 + threadIdx.x;
    if (i < n4a) {
        const float4 v = ((const float4*)a)[i];
        bf16x4 hv = {(bf16_t)v.x, (bf16_t)v.y, (bf16_t)v.z, (bf16_t)v.w};
        ((bf16x4*)ah)[i] = hv;
        return;
    }
    i -= n4a;
    if (i < n4b) {
        const float4 v = ((const float4*)b)[i];
        bf16x4 hv = {(bf16_t)v.x, (bf16_t)v.y, (bf16_t)v.z, (bf16_t)v.w};
        ((bf16x4*)bh)[i] = hv;
        return;
    }
    i -= n4b;
    if (i >= n4c + n4d) {
        i -= n4c + n4d;
        if (i < n4e) {
            const float4 v = ((const float4*)e)[i];
            bf16x4 hv = {(bf16_t)v.x, (bf16_t)v.y, (bf16_t)v.z, (bf16_t)v.w};
            ((bf16x4*)eh)[i] = hv;
        }
        return;
    }
    const float* src; bf16_t* hp; bf16_t* lp;
    if (i < n4c) { src = c; hp = ch; lp = cl; }
    else         { i -= n4c; src = d; hp = dh; lp = dl; }

    const float4 v = ((const float4*)src)[i];
    const bf16_t h0 = (bf16_t)v.x, h1 = (bf16_t)v.y,
                 h2 = (bf16_t)v.z, h3 = (bf16_t)v.w;
    bf16x4 hv = {h0, h1, h2, h3};
    bf16x4 lv = {(bf16_t)(v.x - (float)h0), (bf16_t)(v.y - (float)h1),
                 (bf16_t)(v.z - (float)h2), (bf16_t)(v.w - (float)h3)};
    ((bf16x4*)hp)[i] = hv;
    ((bf16x4*)lp)[i] = lv;
}

// ---------------------------------------------------------------------------
// x_proj split-K reduce + dt-slice hi/lo emit.
// ---------------------------------------------------------------------------
__global__ __launch_bounds__(256) void add8_split(
    const float* __restrict__ p, float* __restrict__ o,
    bf16_t* __restrict__ dth, bf16_t* __restrict__ dtl,
    int n4, size_t stride4)
{
    const int i = blockIdx.x * 256 + threadIdx.x;
    if (i >= n4) return;
    float4 s = make_float4(0.f, 0.f, 0.f, 0.f);
#pragma unroll
    for (int k = 0; k < 8; ++k) {
        const float4 v = ((const float4*)p)[(size_t)k * stride4 + i];
        s.x += v.x; s.y += v.y; s.z += v.z; s.w += v.w;
    }
    ((float4*)o)[i] = s;

    const int col4 = i % 24;
    if (col4 < 16) {
        const int row = i / 24;
        const bf16_t h0 = (bf16_t)s.x, h1 = (bf16_t)s.y,
                     h2 = (bf16_t)s.z, h3 = (bf16_t)s.w;
        bf16x4 hv = {h0, h1, h2, h3};
        bf16x4 lv = {(bf16_t)(s.x - (float)h0), (bf16_t)(s.y - (float)h1),
                     (bf16_t)(s.z - (float)h2), (bf16_t)(s.w - (float)h3)};
        ((bf16x4*)dth)[(size_t)row * 16 + col4] = hv;
        ((bf16x4*)dtl)[(size_t)row * 16 + col4] = lv;
    }
}

// ---------------------------------------------------------------------------
// in_proj, 256x256 tile, 3-PHASE counted-vmcnt schedule + T1 XCD SWIZZLE:
//   linear wgid remapped (orig%8)*64 + orig/8 (bijective, nwg=512) so each
//   XCD's L2 keeps one w1 panel + contiguous A rows resident (R33: FETCH
//   was 49.2 MB vs 25.2 ideal -> L2-miss overfetch).
//   Full 3-bit XOR swizzle (elem col ^= (row&7)<<3) -> conflict-free LDS.
// ---------------------------------------------------------------------------
__global__ __launch_bounds__(512, 1) void in_proj_8ph(
    const bf16_t* __restrict__ Ah, const bf16_t* __restrict__ Wh,
    bf16_t* __restrict__ X, bf16_t* __restrict__ Z, int Ktot)
{
    // lds[buf][mat(0=A,1=B)][half][128*64]
    __shared__ __align__(16) bf16_t lds[2][2][2][128 * 64];

    const int tid  = threadIdx.x;
    const int lane = tid & 63;
    const int wid  = tid >> 6;
    const int wm   = wid >> 2;        // 0..1  (m-half of C)
    const int wn   = wid & 3;         // 0..3  (n-quarter of C)
    const int l16  = lane & 15;
    const int lhi  = lane >> 4;

    // T1 XCD swizzle: nwg = 32*16 = 512, q = 64.
    const int orig = blockIdx.y * gridDim.x + blockIdx.x;
    const int swz  = (orig & 7) * 64 + (orig >> 3);
    const int bxi  = swz & 31;          // gridDim.x == 32
    const int byi  = swz >> 5;

    const int bm  = bxi * 256;
    const int bnW = byi * 256;

    // staging geometry: per half-tile (128x64) each thread does 2 x 16B
    const int srow = tid >> 3;            // 0..63
    const int scol = (tid & 7) * 8;       // element col 0..56
    const int sflip = (srow & 7) << 3;    // full 3-bit swizzle (16B-slot XOR)

    f32x4 acc[8][4];
#pragma unroll
    for (int i = 0; i < 8; ++i)
#pragma unroll
        for (int j = 0; j < 4; ++j)
#pragma unroll
            for (int r = 0; r < 4; ++r) acc[i][j][r] = 0.f;

    const int NT = Ktot >> 6;   // K-tiles of 64

    // ordered stage: early-6 first (A j=0 both halves, all 4 B), late-2 last
    // (A j=1 both halves, read only by the a1 phase).
    auto STAGE_TILE = [&](int pbuf, int kt) {
        const int kc = kt * 64 + (scol ^ sflip);
#pragma unroll
        for (int h = 0; h < 2; ++h) {   // A j=0: rows 0-63 of each half
            const int row = h * 128 + srow;
            GLOAD_LDS16(Ah + (size_t)(bm + row) * Ktot + kc,
                        (char*)&lds[pbuf][0][h][0] + tid * 16);
        }
#pragma unroll
        for (int h = 0; h < 2; ++h)     // B: all rows (read at ph0/ph1)
#pragma unroll
            for (int j = 0; j < 2; ++j) {
                const int row = h * 128 + j * 64 + srow;
                GLOAD_LDS16(Wh + (size_t)(bnW + row) * Ktot + kc,
                            (char*)&lds[pbuf][1][h][0] + (j * 512 + tid) * 16);
            }
#pragma unroll
        for (int h = 0; h < 2; ++h) {   // A j=1: rows 64-127 (a1 phase only)
            const int row = h * 128 + 64 + srow;
            GLOAD_LDS16(Ah + (size_t)(bm + row) * Ktot + kc,
                        (char*)&lds[pbuf][0][h][0] + (512 + tid) * 16);
        }
    };

    const int rflip = (l16 & 7) << 3;     // read-side swizzle (row&7 == l16&7)
    auto A_FRAG = [&](int p, int fm, int kk) -> bf16x8 {
        return *(const bf16x8*)&lds[p][0][wm]
            [(fm * 16 + l16) * 64 + ((kk * 32 + lhi * 8) ^ rflip)];
    };
    auto B_FRAG = [&](int p, int fn, int kk) -> bf16x8 {
        return *(const bf16x8*)&lds[p][1][wn >> 1]
            [((wn & 1) * 64 + fn * 16 + l16) * 64 + ((kk * 32 + lhi * 8) ^ rflip)];
    };

    // prologue: stage tile 0, full drain, barrier
    STAGE_TILE(0, 0);
    SCHED_FENCE();
    asm volatile("s_waitcnt vmcnt(0)" ::: "memory");
    __builtin_amdgcn_s_barrier();
    SCHED_FENCE();

    for (int kt = 0; kt < NT; ++kt) {
        const int p  = kt & 1;
        const int pn = p ^ 1;
        bf16x8 a0[4][2], a1[4][2], b0[2][2], b1[2][2];

        // ---- phase 0: read a0,b0; stage next tile (ordered) ----
#pragma unroll
        for (int f = 0; f < 4; ++f)
#pragma unroll
            for (int kk = 0; kk < 2; ++kk) a0[f][kk] = A_FRAG(p, f, kk);
#pragma unroll
        for (int f = 0; f < 2; ++f)
#pragma unroll
            for (int kk = 0; kk < 2; ++kk) b0[f][kk] = B_FRAG(p, f, kk);
        if (kt + 1 < NT) STAGE_TILE(pn, kt + 1);
        SCHED_FENCE();
        __builtin_amdgcn_s_barrier();
        SCHED_FENCE();
        __builtin_amdgcn_s_setprio(1);
#pragma unroll
        for (int f = 0; f < 4; ++f)
#pragma unroll
            for (int n = 0; n < 2; ++n)
#pragma unroll
                for (int kk = 0; kk < 2; ++kk)
                    acc[f][n] = __builtin_amdgcn_mfma_f32_16x16x32_bf16(
                        a0[f][kk], b0[n][kk], acc[f][n], 0, 0, 0);
        __builtin_amdgcn_s_setprio(0);
        SCHED_FENCE();
        __builtin_amdgcn_s_barrier();
        SCHED_FENCE();

        // ---- phase 1: read b1; MFMA a0 x b1; guard late-2 of tile kt ----
#pragma unroll
        for (int f = 0; f < 2; ++f)
#pragma unroll
            for (int kk = 0; kk < 2; ++kk) b1[f][kk] = B_FRAG(p, f + 2, kk);
        SCHED_FENCE();
        __builtin_amdgcn_s_barrier();
        SCHED_FENCE();
        __builtin_amdgcn_s_setprio(1);
#pragma unroll
        for (int f = 0; f < 4; ++f)
#pragma unroll
            for (int n = 0; n < 2; ++n)
#pragma unroll
                for (int kk = 0; kk < 2; ++kk)
                    acc[f][n + 2] = __builtin_amdgcn_mfma_f32_16x16x32_bf16(
                        a0[f][kk], b1[n][kk], acc[f][n + 2], 0, 0, 0);
        __builtin_amdgcn_s_setprio(0);
        SCHED_FENCE();
        // late-2 A loads of CURRENT tile kt must land before a1 reads.
        if (kt + 1 < NT) { asm volatile("s_waitcnt vmcnt(8)" ::: "memory"); }
        else             { asm volatile("s_waitcnt vmcnt(0)" ::: "memory"); }
        SCHED_FENCE();
        __builtin_amdgcn_s_barrier();
        SCHED_FENCE();

        // ---- phase 2: read a1; MFMA a1 x b0 + a1 x b1; counted drain ----
#pragma unroll
        for (int f = 0; f < 4; ++f)
#pragma unroll
            for (int kk = 0; kk < 2; ++kk) a1[f][kk] = A_FRAG(p, f + 4, kk);
        SCHED_FENCE();
        __builtin_amdgcn_s_barrier();
        SCHED_FENCE();
        __builtin_amdgcn_s_setprio(1);
#pragma unroll
        for (int f = 0; f < 4; ++f)
#pragma unroll
            for (int n = 0; n < 2; ++n)
#pragma unroll
                for (int kk = 0; kk < 2; ++kk)
                    acc[f + 4][n] = __builtin_amdgcn_mfma_f32_16x16x32_bf16(
                        a1[f][kk], b0[n][kk], acc[f + 4][n], 0, 0, 0);
#pragma unroll
        for (int f = 0; f < 4; ++f)
#pragma unroll
            for (int n = 0; n < 2; ++n)
#pragma unroll
                for (int kk = 0; kk < 2; ++kk)
                    acc[f + 4][n + 2] = __builtin_amdgcn_mfma_f32_16x16x32_bf16(
                        a1[f][kk], b1[n][kk], acc[f + 4][n + 2], 0, 0, 0);
        __builtin_amdgcn_s_setprio(0);
        SCHED_FENCE();
        // drain early-6 of tile kt+1; leave its late-2 flying into next iter.
        asm volatile("s_waitcnt vmcnt(2)" ::: "memory");
        SCHED_FENCE();
        __builtin_amdgcn_s_barrier();
        SCHED_FENCE();
    }

    bf16_t* outp = (byi < 8) ? X : Z;
    const int bnC = ((byi < 8) ? byi : (byi - 8)) * 256;
#pragma unroll
    for (int fm = 0; fm < 8; ++fm) {
        const int row0 = bm + wm * 128 + fm * 16 + lhi * 4;
#pragma unroll
        for (int fn = 0; fn < 4; ++fn) {
            const int col = bnC + wn * 64 + fn * 16 + l16;
#pragma unroll
            for (int r = 0; r < 4; ++r)
                outp[(size_t)(row0 + r) * 2048 + col] = (bf16_t)acc[fm][fn][r];
        }
    }
}

// ---------------------------------------------------------------------------
// dt_proj: 3-term MFMA (dt pair x wd pair), K=64; softplus; bf16 OUTPUT.
// 128x128 tile, BK=32, 48 MFMA/step.
// ---------------------------------------------------------------------------
__global__ __launch_bounds__(256) void gemm_mfma3dt(
    const bf16_t* __restrict__ Ah, const bf16_t* __restrict__ Al,
    const bf16_t* __restrict__ Bh, const bf16_t* __restrict__ Bl,
    bf16_t* __restrict__ C, const float* __restrict__ bias,
    int Ktot, int ldc)
{
    __shared__ __align__(16) bf16_t Ash[128 * 32];
    __shared__ __align__(16) bf16_t Asl[128 * 32];
    __shared__ __align__(16) bf16_t Bsh[128 * 32];
    __shared__ __align__(16) bf16_t Bsl[128 * 32];

    const int tid  = threadIdx.x;
    const int lane = tid & 63;
    const int w    = tid >> 6;
    const int wr   = (w >> 1) * 64;
    const int wc   = (w & 1) * 64;
    const int bm   = blockIdx.x * 128;
    const int bn   = blockIdx.y * 128;
    const int l16  = lane & 15;
    const int lhi  = lane >> 4;

    f32x4 acc[4][4];
#pragma unroll
    for (int i = 0; i < 4; ++i)
#pragma unroll
        for (int j = 0; j < 4; ++j)
#pragma unroll
            for (int r = 0; r < 4; ++r) acc[i][j][r] = 0.f;

    const int srow0 = tid >> 2;
    const int sks   = (tid & 3) << 3;
    const int ldsb0 = tid * 16;

    for (int k0 = 0; k0 < Ktot; k0 += 32) {
        __syncthreads();
#pragma unroll
        for (int call = 0; call < 2; ++call) {
            const int row = srow0 + call * 64;
            const int wb  = ldsb0 + call * 4096;
            const size_t aoff = (size_t)(bm + row) * Ktot + k0 + sks;
            const size_t boff = (size_t)(bn + row) * Ktot + k0 + sks;
            GLOAD_LDS16(Ah + aoff, (char*)Ash + wb);
            GLOAD_LDS16(Al + aoff, (char*)Asl + wb);
            GLOAD_LDS16(Bh + boff, (char*)Bsh + wb);
            GLOAD_LDS16(Bl + boff, (char*)Bsl + wb);
        }
        __syncthreads();

        bf16x8 ah[4], al[4], bh[4], bl[4];
#pragma unroll
        for (int f = 0; f < 4; ++f) {
            const int ar = (wr + f * 16 + l16) * 32 + lhi * 8;
            const int br = (wc + f * 16 + l16) * 32 + lhi * 8;
            ah[f] = *(const bf16x8*)&Ash[ar];
            al[f] = *(const bf16x8*)&Asl[ar];
            bh[f] = *(const bf16x8*)&Bsh[br];
            bl[f] = *(const bf16x8*)&Bsl[br];
        }
#pragma unroll
        for (int fm = 0; fm < 4; ++fm)
#pragma unroll
            for (int fn = 0; fn < 4; ++fn) {
                acc[fm][fn] = __builtin_amdgcn_mfma_f32_16x16x32_bf16(
                    ah[fm], bh[fn], acc[fm][fn], 0, 0, 0);
                acc[fm][fn] = __builtin_amdgcn_mfma_f32_16x16x32_bf16(
                    al[fm], bh[fn], acc[fm][fn], 0, 0, 0);
                acc[fm][fn] = __builtin_amdgcn_mfma_f32_16x16x32_bf16(
                    ah[fm], bl[fn], acc[fm][fn], 0, 0, 0);
            }
    }

#pragma unroll
    for (int fm = 0; fm < 4; ++fm) {
        const int row0 = bm + wr + fm * 16 + lhi * 4;
#pragma unroll
        for (int fn = 0; fn < 4; ++fn) {
            const int col = bn + wc + fn * 16 + l16;
#pragma unroll
            for (int r = 0; r < 4; ++r) {
                float v = acc[fm][fn][r] + bias[col];
                v = (v > 20.f) ? v : log1pf(expf(v));
                C[(size_t)(row0 + r) * ldc + col] = (bf16_t)v;
            }
        }
    }
}

// ---------------------------------------------------------------------------
// x_proj, 2-TERM MFMA (A single bf16 x B pair), split-K.
// ---------------------------------------------------------------------------
__global__ __launch_bounds__(256) void gemm_mfma2x(
    const bf16_t* __restrict__ Ah,
    const bf16_t* __restrict__ Bh, const bf16_t* __restrict__ Bl,
    float* __restrict__ C, int Ktot, int Ksplit, size_t partStride)
{
    __shared__ __align__(16) bf16_t Ash[128 * 32];
    __shared__ __align__(16) bf16_t Bsh[128 * 32];
    __shared__ __align__(16) bf16_t Bsl[128 * 32];

    const int tid  = threadIdx.x;
    const int lane = tid & 63;
    const int w    = tid >> 6;
    const int wr   = (w >> 1) * 64;
    const int wc   = (w & 1) * 64;
    const int bm   = blockIdx.x * 128;
    const int l16  = lane & 15;
    const int lhi  = lane >> 4;

    f32x4 acc[4][4];
#pragma unroll
    for (int i = 0; i < 4; ++i)
#pragma unroll
        for (int j = 0; j < 4; ++j)
#pragma unroll
            for (int r = 0; r < 4; ++r) acc[i][j][r] = 0.f;

    const int srow0 = tid >> 2;
    const int sks   = (tid & 3) << 3;
    const int ldsb0 = tid * 16;

    const int kBeg = blockIdx.z * Ksplit;
    const int kEnd = kBeg + Ksplit;

    for (int k0 = kBeg; k0 < kEnd; k0 += 32) {
        __syncthreads();
#pragma unroll
        for (int call = 0; call < 2; ++call) {
            const int row  = srow0 + call * 64;
            const int brow = (row < 96) ? row : 95;
            const int wb   = ldsb0 + call * 4096;
            const size_t aoff = (size_t)(bm + row) * Ktot + k0 + sks;
            const size_t boff = (size_t)brow * Ktot + k0 + sks;
            GLOAD_LDS16(Ah + aoff, (char*)Ash + wb);
            GLOAD_LDS16(Bh + boff, (char*)Bsh + wb);
            GLOAD_LDS16(Bl + boff, (char*)Bsl + wb);
        }
        __syncthreads();

        bf16x8 ah[4], bh[4], bl[4];
#pragma unroll
        for (int f = 0; f < 4; ++f) {
            const int ar = (wr + f * 16 + l16) * 32 + lhi * 8;
            const int br = (wc + f * 16 + l16) * 32 + lhi * 8;
            ah[f] = *(const bf16x8*)&Ash[ar];
            bh[f] = *(const bf16x8*)&Bsh[br];
            bl[f] = *(const bf16x8*)&Bsl[br];
        }
#pragma unroll
        for (int fm = 0; fm < 4; ++fm)
#pragma unroll
            for (int fn = 0; fn < 4; ++fn) {
                acc[fm][fn] = __builtin_amdgcn_mfma_f32_16x16x32_bf16(
                    ah[fm], bh[fn], acc[fm][fn], 0, 0, 0);
                acc[fm][fn] = __builtin_amdgcn_mfma_f32_16x16x32_bf16(
                    ah[fm], bl[fn], acc[fm][fn], 0, 0, 0);
            }
    }

    float* Cp = C + (size_t)blockIdx.z * partStride;
#pragma unroll
    for (int fm = 0; fm < 4; ++fm) {
        const int row0 = bm + wr + fm * 16 + lhi * 4;
#pragma unroll
        for (int fn = 0; fn < 4; ++fn) {
            const int col = wc + fn * 16 + l16;
            if (col < 96) {
#pragma unroll
                for (int r = 0; r < 4; ++r)
                    Cp[(size_t)(row0 + r) * 96 + col] = acc[fm][fn][r];
            }
        }
    }
}

// ---------------------------------------------------------------------------
// out_proj (1-TERM, 128x128 tile, NO SPLIT-K): C = Ah.Bh^T direct to out.
// ---------------------------------------------------------------------------
__global__ __launch_bounds__(256) void gemm_mfma1o128(
    const bf16_t* __restrict__ Ah, const bf16_t* __restrict__ Bh,
    float* __restrict__ C, int K, int ldc)
{
    __shared__ __align__(16) bf16_t Ash[128 * 32];
    __shared__ __align__(16) bf16_t Bsh[128 * 32];

    const int tid  = threadIdx.x;
    const int lane = tid & 63;
    const int w    = tid >> 6;
    const int wr   = (w >> 1) * 64;
    const int wc   = (w & 1) * 64;
    const int bm   = blockIdx.x * 128;
    const int bn   = blockIdx.y * 128;
    const int l16  = lane & 15;
    const int lhi  = lane >> 4;

    f32x4 acc[4][4];
#pragma unroll
    for (int i = 0; i < 4; ++i)
#pragma unroll
        for (int j = 0; j < 4; ++j)
#pragma unroll
            for (int r = 0; r < 4; ++r) acc[i][j][r] = 0.f;

    const int srow0 = tid >> 2;
    const int sks   = (tid & 3) << 3;
    const int ldsb0 = tid * 16;

    for (int k0 = 0; k0 < K; k0 += 32) {
        __syncthreads();
#pragma unroll
        for (int call = 0; call < 2; ++call) {
            const int row = srow0 + call * 64;
            const int wb  = ldsb0 + call * 4096;
            GLOAD_LDS16(Ah + (size_t)(bm + row) * K + k0 + sks, (char*)Ash + wb);
            GLOAD_LDS16(Bh + (size_t)(bn + row) * K + k0 + sks, (char*)Bsh + wb);
        }
        __syncthreads();

        bf16x8 af[4], bfr[4];
#pragma unroll
        for (int f = 0; f < 4; ++f) {
            af[f]  = *(const bf16x8*)&Ash[(wr + f * 16 + l16) * 32 + lhi * 8];
            bfr[f] = *(const bf16x8*)&Bsh[(wc + f * 16 + l16) * 32 + lhi * 8];
        }
#pragma unroll
        for (int fm = 0; fm < 4; ++fm)
#pragma unroll
            for (int fn = 0; fn < 4; ++fn)
                acc[fm][fn] = __builtin_amdgcn_mfma_f32_16x16x32_bf16(
                    af[fm], bfr[fn], acc[fm][fn], 0, 0, 0);
    }

#pragma unroll
    for (int fm = 0; fm < 4; ++fm) {
        const int row0 = bm + wr + fm * 16 + lhi * 4;
#pragma unroll
        for (int fn = 0; fn < 4; ++fn) {
            const int col = bn + wc + fn * 16 + l16;
#pragma unroll
            for (int r = 0; r < 4; ++r)
                C[(size_t)(row0 + r) * ldc + col] = acc[fm][fn][r];
        }
    }
}

// ---------------------------------------------------------------------------
// Depthwise causal conv (width 4) + bias + SiLU; INPUT bf16, 8 ch/thread;
// output SINGLE bf16.  SiLU via fast rcp (1-ulp; invisible under bf16).
// ---------------------------------------------------------------------------
__global__ __launch_bounds__(256) void conv_silu8s(
    const bf16_t* __restrict__ xin, const float* __restrict__ w,
    const float* __restrict__ bias,
    bf16_t* __restrict__ xh,
    int L, int D)
{
    const long long e8 = (long long)blockIdx.x * 256 + threadIdx.x;
    const int Dq = D >> 3;
    const int dq = (int)(e8 % Dq);
    const long long bl = e8 / Dq;
    const int l = (int)(bl % L);
    const int d = dq << 3;
    const long long base = bl * D + d;

    float t0[8], t1[8], t2[8], t3[8];
    {
        const bf16x8 v = *(const bf16x8*)&xin[base];
#pragma unroll
        for (int j = 0; j < 8; ++j) t0[j] = (float)v[j];
    }
    if (l >= 1) { const bf16x8 v = *(const bf16x8*)&xin[base - D];
#pragma unroll
        for (int j = 0; j < 8; ++j) t1[j] = (float)v[j];
    } else { for (int j = 0; j < 8; ++j) t1[j] = 0.f; }
    if (l >= 2) { const bf16x8 v = *(const bf16x8*)&xin[base - 2 * D];
#pragma unroll
        for (int j = 0; j < 8; ++j) t2[j] = (float)v[j];
    } else { for (int j = 0; j < 8; ++j) t2[j] = 0.f; }
    if (l >= 3) { const bf16x8 v = *(const bf16x8*)&xin[base - 3 * D];
#pragma unroll
        for (int j = 0; j < 8; ++j) t3[j] = (float)v[j];
    } else { for (int j = 0; j < 8; ++j) t3[j] = 0.f; }

    bf16x8 hv;
#pragma unroll
    for (int j = 0; j < 8; ++j) {
        const float4 wv = *(const float4*)&w[(d + j) * 4];
        float acc = bias[d + j];
        acc = fmaf(wv.w, t0[j], acc);
        acc = fmaf(wv.z, t1[j], acc);
        acc = fmaf(wv.y, t2[j], acc);
        acc = fmaf(wv.x, t3[j], acc);
        const float o = acc * __builtin_amdgcn_rcpf(1.f + __expf(-acc));
        hv[j] = (bf16_t)o;
    }
    *(bf16x8*)&xh[base] = hv;
}

// ---------------------------------------------------------------------------
// Scan pass 1 (per-channel): x bf16 single, dt bf16.  CH=64.
// B read as 4 x ds_read_b128 per timestep.  Emits Sbuf + Dsum (sumdt only;
// P recomputed in pass 2 -- saves the 16.8 MB Pbuf round-trip).
// ---------------------------------------------------------------------------
__global__ __launch_bounds__(256) void scan_local2(
    const bf16_t* __restrict__ xh,
    const bf16_t* __restrict__ dtb,
    const float* __restrict__ xdbl,  const float* __restrict__ A_log,
    float* __restrict__ Sbuf, float* __restrict__ Dsum)
{
    __shared__ __align__(16) float Bs[CH][16];

    const int d = blockIdx.x * 256 + threadIdx.x;
    const int c = blockIdx.y;
    const int b = blockIdx.z;
    const long long rowBase = (long long)b * 4096 + (long long)c * CH;

    {
        const int e = threadIdx.x;
        const int i = e >> 2, j = (e & 3) << 2;
        *(float4*)&Bs[i][j] = *(const float4*)&xdbl[(rowBase + i) * 96 + 64 + j];
    }
    __syncthreads();

    float a[16], S[16];
#pragma unroll
    for (int n = 0; n < 16; ++n) {
        a[n] = -__expf(A_log[d * 16 + n]);
        S[n] = 0.f;
    }
    float sumdt = 0.f;

    for (int i = 0; i < CH; ++i) {
        const long long row = rowBase + i;
        const float dtv = (float)dtb[row * 2048 + d];
        const float xv  = (float)xh[row * 2048 + d];
        const float u   = dtv * xv;
        sumdt += dtv;

        const f32x4 bv0 = *(const f32x4*)&Bs[i][0];
        const f32x4 bv1 = *(const f32x4*)&Bs[i][4];
        const f32x4 bv2 = *(const f32x4*)&Bs[i][8];
        const f32x4 bv3 = *(const f32x4*)&Bs[i][12];
        float bb[16];
#pragma unroll
        for (int q = 0; q < 4; ++q) {
            bb[q]      = bv0[q];
            bb[4 + q]  = bv1[q];
            bb[8 + q]  = bv2[q];
            bb[12 + q] = bv3[q];
        }
#pragma unroll
        for (int n = 0; n < 16; ++n) {
            const float dA = __expf(dtv * a[n]);
            S[n] = fmaf(S[n], dA, u * bb[n]);
        }
    }

    const size_t base = ((((size_t)b * NC + c) * 2048) + d) * 16;
#pragma unroll
    for (int k = 0; k < 4; ++k) {
        *(float4*)&Sbuf[base + k * 4] =
            make_float4(S[k*4], S[k*4+1], S[k*4+2], S[k*4+3]);
    }
    Dsum[((size_t)b * NC + c) * 2048 + d] = sumdt;
}

// ---------------------------------------------------------------------------
// Pass 2: sequential prefix over NC=64 chunks.  P recomputed from Dsum:
// P[n] = exp(sumdt * a[n]) -- same formula/inputs as before (bit-identical).
// ---------------------------------------------------------------------------
__global__ __launch_bounds__(256) void scan_chunk_prefix(
    float* __restrict__ Sbuf, const float* __restrict__ Dsum,
    const float* __restrict__ A_log)
{
    const int tid = blockIdx.x * 256 + threadIdx.x;
    const int b  = tid >> 15;
    const int dn = tid & 32767;
    const int d  = dn >> 4;

    const float a = -__expf(A_log[dn]);

    float H = 0.f;
    for (int c = 0; c < NC; ++c) {
        const size_t idx = ((size_t)b * NC + c) * 32768 + dn;
        const float S = Sbuf[idx];
        const float sumdt = Dsum[((size_t)b * NC + c) * 2048 + d];
        const float P = __expf(sumdt * a);
        Sbuf[idx] = H;
        H = fmaf(P, H, S);
    }
}

// ---------------------------------------------------------------------------
// Scan pass 3: x single, dt bf16, z bf16; y written bf16 in-place over xh.
// B/C read as 8 x ds_read_b128 per timestep; SiLU via rcp.  CH=64.
// ---------------------------------------------------------------------------
__global__ __launch_bounds__(256) void scan_final2(
    const bf16_t* __restrict__ xh,
    const bf16_t* __restrict__ dtb,
    const float* __restrict__ xdbl,  const float* __restrict__ A_log,
    const float* __restrict__ Dp,    const bf16_t* __restrict__ z,
    const float* __restrict__ Hbuf,  bf16_t* __restrict__ y)
{
    __shared__ __align__(16) float BCs[CH][32];

    const int d = blockIdx.x * 256 + threadIdx.x;
    const int c = blockIdx.y;
    const int b = blockIdx.z;
    const long long rowBase = (long long)b * 4096 + (long long)c * CH;

#pragma unroll
    for (int k = 0; k < 2; ++k) {
        const int e = k * 256 + threadIdx.x;
        const int i = e >> 3, j = (e & 7) << 2;
        *(float4*)&BCs[i][j] = *(const float4*)&xdbl[(rowBase + i) * 96 + 64 + j];
    }
    __syncthreads();

    float a[16], h[16];
    const size_t hbase = ((((size_t)b * NC + c) * 2048) + d) * 16;
#pragma unroll
    for (int k = 0; k < 4; ++k) {
        const float4 hv = *(const float4*)&Hbuf[hbase + k * 4];
        h[k*4] = hv.x; h[k*4+1] = hv.y; h[k*4+2] = hv.z; h[k*4+3] = hv.w;
    }
#pragma unroll
    for (int n = 0; n < 16; ++n) a[n] = -__expf(A_log[d * 16 + n]);
    const float Dv = Dp[d];

    for (int i = 0; i < CH; ++i) {
        const long long row = rowBase + i;
        const float dtv = (float)dtb[row * 2048 + d];
        const float xv  = (float)xh[row * 2048 + d];
        const float u   = dtv * xv;

        const f32x4 bv0 = *(const f32x4*)&BCs[i][0];
        const f32x4 bv1 = *(const f32x4*)&BCs[i][4];
        const f32x4 bv2 = *(const f32x4*)&BCs[i][8];
        const f32x4 bv3 = *(const f32x4*)&BCs[i][12];
        const f32x4 cv0 = *(const f32x4*)&BCs[i][16];
        const f32x4 cv1 = *(const f32x4*)&BCs[i][20];
        const f32x4 cv2 = *(const f32x4*)&BCs[i][24];
        const f32x4 cv3 = *(const f32x4*)&BCs[i][28];
        float bb[16], cc[16];
#pragma unroll
        for (int q = 0; q < 4; ++q) {
            bb[q]      = bv0[q];  cc[q]      = cv0[q];
            bb[4 + q]  = bv1[q];  cc[4 + q]  = cv1[q];
            bb[8 + q]  = bv2[q];  cc[8 + q]  = cv2[q];
            bb[12 + q] = bv3[q];  cc[12 + q] = cv3[q];
        }

        float acc = 0.f;
#pragma unroll
        for (int n = 0; n < 16; ++n) {
            const float dA = __expf(dtv * a[n]);
            h[n] = fmaf(h[n], dA, u * bb[n]);
            acc  = fmaf(h[n], cc[n], acc);
        }
        const float zv = (float)z[row * 2048 + d];
        float yv = acc + xv * Dv;
        yv = yv * (zv * __builtin_amdgcn_rcpf(1.f + __expf(-zv)));
        y[row * 2048 + d] = (bf16_t)yv;
    }
}

// ---------------------------------------------------------------------------
extern "C" void kernel_launch(void* const* d_in, const int* in_sizes, int n_in,
                              void* d_out, int out_size, void* d_ws, size_t ws_size,
                              hipStream_t stream)
{
    const float* hidden     = (const float*)d_in[0];
    const float* in_proj_w  = (const float*)d_in[1];
    const float* conv_w     = (const float*)d_in[2];
    const float* conv_b     = (const float*)d_in[3];
    const float* x_proj_w   = (const float*)d_in[4];
    const float* dt_proj_w  = (const float*)d_in[5];
    const float* dt_proj_b  = (const float*)d_in[6];
    const float* A_log      = (const float*)d_in[7];
    const float* Dvec       = (const float*)d_in[8];
    const float* out_proj_w = (const float*)d_in[9];
    float* out = (float*)d_out;

    const int L = 4096, dinner = 2048, dmodel = 1024;
    const int M = 2 * L;  // 8192

    // ---- workspace layout (R2 footprint preserved) ----
    float* z     = (float*)d_ws;
    float* xraw  = z     + (size_t)M * dinner;
    float* xconv = xraw  + (size_t)M * dinner;
    float* xdbl  = xconv + (size_t)M * dinner;
    float* Sbuf  = xdbl  + (size_t)M * 96;             // 16.8 MB region

    bf16_t* w1_h  = (bf16_t*)Sbuf;                     // hi only, 8.4 MB (t0..in_proj)
    bf16_t* hid_h = (bf16_t*)xconv;
    bf16_t* zb    = (bf16_t*)z;
    bf16_t* Xb    = (bf16_t*)xraw;                     // x bf16 (33.5 MB)
    bf16_t* xc_h  = (bf16_t*)xconv;                    // conv out, single bf16
    float*  xp_part = xraw;                            // x_proj partials (Xb dead post-conv)
    bf16_t* dtb  = (bf16_t*)xraw;                      // dt bf16 (partials dead post-add8)
    bf16_t* dth  = (bf16_t*)Sbuf;
    bf16_t* dtl  = dth + (size_t)M * 64;
    bf16_t* wdh  = (bf16_t*)out;                       // d_out region (dead pre-step6)
    bf16_t* wdl  = wdh + (size_t)dinner * 64;
    bf16_t* xpwh = (bf16_t*)xdbl;                      // xdbl region (pre-add8)
    bf16_t* xpwl = xpwh + (size_t)96 * dinner;
    bf16_t* w2_h = zb + (size_t)M * dinner;            // z + 33.5 MB (hi only)
    float*  Dsum = (float*)(w2_h + (size_t)dmodel * dinner);  // z + 37.7 MB (1 MB)

    // ---- 0. mega t=0 split ----
    const int n4a = M * dmodel / 4;
    const int n4b = 2 * dinner * dmodel / 4;
    const int n4c = dinner * 64 / 4;
    const int n4d = 96 * dinner / 4;
    const int n4e = dmodel * dinner / 4;
    split5n<<<(n4a + n4b + n4c + n4d + n4e + 255) / 256, 256, 0, stream>>>(
        hidden, hid_h, n4a,
        in_proj_w, w1_h, n4b,
        dt_proj_w, wdh, wdl, n4c,
        x_proj_w, xpwh, xpwl, n4d,
        out_proj_w, w2_h, n4e);

    // ---- 1. in_proj (256^2 3-phase + XCD swizzle; x bf16 | z bf16) ----
    in_proj_8ph<<<dim3(M / 256, 16), 512, 0, stream>>>(
        hid_h, w1_h, Xb, zb, dmodel);

    // ---- 2. conv + bias + SiLU (bf16 in) -> bf16 single ----
    conv_silu8s<<<(M * (long long)dinner / 8) / 256, 256, 0, stream>>>(
        Xb, conv_w, conv_b, xc_h, L, dinner);

    // ---- 3. x_proj (2-term MFMA, split-K=8) ----
    gemm_mfma2x<<<dim3(M / 128, 1, 8), 256, 0, stream>>>(
        xc_h, xpwh, xpwl, xp_part, dinner, dinner / 8, (size_t)M * 96);
    add8_split<<<(M * 96 / 4 + 255) / 256, 256, 0, stream>>>(
        xp_part, xdbl, dth, dtl, M * 96 / 4, (size_t)M * 96 / 4);

    // ---- 4. dt_proj (3-term MFMA, K=64) -> dt bf16 (over dead partials) ----
    gemm_mfma3dt<<<dim3(M / 128, 2048 / 128), 256, 0, stream>>>(
        dth, dtl, wdh, wdl, dtb, dt_proj_b, 64, 2048);

    // ---- 5. chunked selective scan (CH=64; Dsum instead of Pbuf) ----
    scan_local2<<<dim3(dinner / 256, NC, 2), 256, 0, stream>>>(
        xc_h, dtb, xdbl, A_log, Sbuf, Dsum);
    scan_chunk_prefix<<<256, 256, 0, stream>>>(Sbuf, Dsum, A_log);
    scan_final2<<<dim3(dinner / 256, NC, 2), 256, 0, stream>>>(
        xc_h, dtb, xdbl, A_log, Dvec, zb, Sbuf, xc_h);

    // ---- 6. out_proj (1-term, 128x128 tile, direct write) ----
    gemm_mfma1o128<<<dim3(M / 128, 1024 / 128), 256, 0, stream>>>(
        xc_h, w2_h, out, dinner, 1024);
}